// Round 1
// baseline (1726.688 us; speedup 1.0000x reference)
//
#include <hip/hip_runtime.h>
#include <stdint.h>

typedef unsigned short u16;
typedef unsigned int   u32;

#define NN 16384   // nodes
#define NE 262144  // edges
#define NG 64      // graphs
#define HD 256     // hidden
#define KC 8       // K/32 (K=256 for every GEMM here)

typedef __attribute__((ext_vector_type(8))) short bfrag;  // 8 bf16 (4 VGPR)
typedef __attribute__((ext_vector_type(4))) float ffrag;  // 4 f32 acc

__device__ __forceinline__ float bf2f(u16 h){
  union { u32 u; float f; } v; v.u = ((u32)h) << 16; return v.f;
}
__device__ __forceinline__ u16 f2bf(float x){
  union { float f; u32 u; } v; v.f = x;
  u32 r = v.u + 0x7fffu + ((v.u >> 16) & 1u);
  return (u16)(r >> 16);
}
__device__ __forceinline__ float sigmoidf(float x){ return 1.f/(1.f+__expf(-x)); }

enum { MODE_SCORE=0, MODE_PRE=1, MODE_OUT=2, MODE_OUT_WE=3, MODE_PQ=4 };

// C[M x 256] = A[M x 256] @ B[256 x 256]  (A bf16 row-major, B pre-repacked frag layout)
// block = 256 thr (4 waves), each wave 32 rows (2 m-tiles), BM=128, no LDS.
// A-frag: lane holds A[m=lane&15][k=c*32+(lane>>4)*8+j]; B-frag symmetric.
// C/D layout: col=lane&15, row=(lane>>4)*4+reg  (per cdna_hip_programming.md §3).
template<int MODE>
__global__ __launch_bounds__(256)
void gemm_k(const u16* __restrict__ A, const u16* __restrict__ Bf,
            float* __restrict__ outF, u16* __restrict__ outB,
            const float* __restrict__ bias, const float* __restrict__ vec,
            const float* __restrict__ scal,
            const u16* __restrict__ Pg, const u16* __restrict__ Qg,
            const int* __restrict__ srcI, const int* __restrict__ recvI,
            const float* __restrict__ flags, const float* __restrict__ ht)
{
  const int l  = threadIdx.x & 63;
  const int w  = threadIdx.x >> 6;
  const int q  = l >> 4;
  const int ml = l & 15;
  const long rowBase = (long)blockIdx.x * 128 + w * 32;

  ffrag acc[2][16];
#pragma unroll
  for (int mt=0; mt<2; ++mt)
#pragma unroll
    for (int n=0; n<16; ++n) acc[mt][n] = (ffrag){0.f,0.f,0.f,0.f};

  const u16* Ar0 = A + (size_t)(rowBase + ml) * HD;
  const u16* Ar1 = Ar0 + (size_t)16 * HD;

#pragma unroll 1
  for (int c=0; c<KC; ++c){
    bfrag a0 = *(const bfrag*)(Ar0 + c*32 + q*8);
    bfrag a1 = *(const bfrag*)(Ar1 + c*32 + q*8);
    const bfrag* bp = (const bfrag*)(Bf + (size_t)c*8192 + l*8);
#pragma unroll
    for (int n=0; n<16; ++n){
      bfrag b = bp[n*64];
      acc[0][n] = __builtin_amdgcn_mfma_f32_16x16x32_bf16(a0, b, acc[0][n], 0, 0, 0);
      acc[1][n] = __builtin_amdgcn_mfma_f32_16x16x32_bf16(a1, b, acc[1][n], 0, 0, 0);
    }
  }

  if constexpr (MODE==MODE_SCORE || MODE==MODE_OUT_WE){
    // fused second layer: reduce over cols of relu(C+b1)*w2 (SCORE) or (C+b2)*ew_w (OUT_WE)
    float part[2][4] = {{0,0,0,0},{0,0,0,0}};
#pragma unroll
    for (int n=0; n<16; ++n){
      const int col = n*16 + ml;
      const float bb = bias[col];
      const float vv = vec[col];
#pragma unroll
      for (int mt=0; mt<2; ++mt)
#pragma unroll
        for (int r=0; r<4; ++r){
          float x = acc[mt][n][r] + bb;
          if (MODE==MODE_SCORE) x = fmaxf(x, 0.f);
          part[mt][r] += x * vv;
        }
    }
#pragma unroll
    for (int mt=0; mt<2; ++mt)
#pragma unroll
      for (int r=0; r<4; ++r){
        float p = part[mt][r];
        p += __shfl_xor(p, 1, 64);
        p += __shfl_xor(p, 2, 64);
        p += __shfl_xor(p, 4, 64);
        p += __shfl_xor(p, 8, 64);
        part[mt][r] = p;
      }
    if (ml == 0){
      const float sc = scal[0];
#pragma unroll
      for (int mt=0; mt<2; ++mt)
#pragma unroll
        for (int r=0; r<4; ++r){
          long row = rowBase + mt*16 + q*4 + r;
          outF[row] = sigmoidf(part[mt][r] + sc);
        }
    }
  } else if constexpr (MODE==MODE_OUT){
#pragma unroll
    for (int mt=0; mt<2; ++mt)
#pragma unroll
      for (int r=0; r<4; ++r){
        long row = rowBase + mt*16 + q*4 + r;
        u16* op = outB + (size_t)row*HD + ml;
#pragma unroll
        for (int n=0; n<16; ++n)
          op[n*16] = f2bf(acc[mt][n][r] + bias[n*16+ml]);
      }
  } else if constexpr (MODE==MODE_PRE){
    // h = relu(b_e@W1c + P[src] + Q[recv])   (b1 folded into P)
#pragma unroll
    for (int mt=0; mt<2; ++mt)
#pragma unroll
      for (int r=0; r<4; ++r){
        long row = rowBase + mt*16 + q*4 + r;
        const int si = srcI[row];
        const int ri = recvI[row];
        const u16* Pr = Pg + (size_t)si*HD + ml;
        const u16* Qr = Qg + (size_t)ri*HD + ml;
        u16* op = outB + (size_t)row*HD + ml;
#pragma unroll
        for (int n=0; n<16; ++n){
          float v = acc[mt][n][r] + bf2f(Pr[n*16]) + bf2f(Qr[n*16]);
          op[n*16] = f2bf(fmaxf(v, 0.f));
        }
      }
  } else { // MODE_PQ: node GEMM + rank-1 head/tail rows (+optional bias)
#pragma unroll
    for (int mt=0; mt<2; ++mt)
#pragma unroll
      for (int r=0; r<4; ++r){
        long row = rowBase + mt*16 + q*4 + r;
        const float fh = flags[2*row];
        const float ft = flags[2*row+1];
        u16* op = outB + (size_t)row*HD + ml;
#pragma unroll
        for (int n=0; n<16; ++n){
          const int col = n*16 + ml;
          float v = acc[mt][n][r] + fh*ht[col] + ft*ht[HD+col];
          if (bias) v += bias[col];
          op[n*16] = f2bf(v);
        }
      }
  }
}

// repack B[256 x 256] f32 row-major -> bf16 MFMA-fragment order:
// out[((c*16+n)*64+l)*8+j] = B[c*32+(l>>4)*8+j][n*16+(l&15)]
__global__ void repack_k(const float* __restrict__ B, u16* __restrict__ out){
  int t = blockIdx.x*256 + threadIdx.x;        // 8192 total
  int l = t & 63, n = (t>>6)&15, c = t>>10;
  int k0 = c*32 + ((l>>4)<<3), col = n*16 + (l&15);
#pragma unroll
  for (int j=0; j<8; ++j)
    out[(size_t)t*8 + j] = f2bf(B[(size_t)(k0+j)*HD + col]);
}

// b_e(iter0) = [edge_features | g_all] -> bf16 row-major
__global__ void initbe_k(const float* __restrict__ ef, const float* __restrict__ gall,
                         u16* __restrict__ BE){
  int t = blockIdx.x*256 + threadIdx.x;        // NE*64
  int e = t >> 6; int c4 = (t & 63) * 4;
  float4 v;
  if (c4 < 192) v = *(const float4*)(ef + (size_t)e*192 + c4);
  else          v = *(const float4*)(gall + (c4 - 192));
  u32 lo = (u32)f2bf(v.x) | ((u32)f2bf(v.y) << 16);
  u32 hi = (u32)f2bf(v.z) | ((u32)f2bf(v.w) << 16);
  uint2 o; o.x = lo; o.y = hi;
  *(uint2*)(BE + (size_t)e*HD + c4) = o;
}

__global__ void flags_k(const int* __restrict__ batch, const int* __restrict__ heads,
                        const int* __restrict__ tails, float* __restrict__ flags){
  int n = blockIdx.x*256 + threadIdx.x;
  int g = batch[n];
  flags[2*n]   = (n == heads[g]) ? 1.f : 0.f;
  flags[2*n+1] = (n == tails[g]) ? 1.f : 0.f;
}

// exclusive prefix sum of degrees -> CSR offsets (+ cursor copy), single block
__global__ void scan_k(const int* __restrict__ deg, int* __restrict__ offs,
                       int* __restrict__ cur){
  __shared__ int part[256];
  int tid = threadIdx.x;
  int base = tid * 64;
  int s = 0;
  for (int j=0; j<64; ++j) s += deg[base+j];
  part[tid] = s;
  __syncthreads();
  if (tid == 0){
    int run = 0;
    for (int i=0; i<256; ++i){ int t = part[i]; part[i] = run; run += t; }
  }
  __syncthreads();
  int run = part[tid];
  for (int j=0; j<64; ++j){
    offs[base+j] = run; cur[base+j] = run; run += deg[base+j];
  }
  if (tid == 255) offs[NN] = run;
}

__global__ void fill_k(const int* __restrict__ recv, int* __restrict__ cur,
                       int* __restrict__ eids){
  int e = blockIdx.x*256 + threadIdx.x;
  int r = recv[e];
  int p = atomicAdd(&cur[r], 1);
  eids[p] = e;
}

// per-node softmax over incoming edges + weighted aggregation, one wave per node
__global__ __launch_bounds__(256)
void agg_k(const float* __restrict__ score, const u16* __restrict__ BE,
           const int* __restrict__ offs, const int* __restrict__ eids,
           float* __restrict__ bv, u16* __restrict__ bvb){
  int node = blockIdx.x*4 + (threadIdx.x >> 6);
  int l = threadIdx.x & 63;
  int beg = offs[node], end = offs[node+1];

  float m = -1e30f;
  for (int i=beg+l; i<end; i+=64) m = fmaxf(m, score[eids[i]]);
#pragma unroll
  for (int d=1; d<64; d<<=1) m = fmaxf(m, __shfl_xor(m, d, 64));

  float s = 0.f;
  for (int i=beg+l; i<end; i+=64) s += __expf(score[eids[i]] - m);
#pragma unroll
  for (int d=1; d<64; d<<=1) s += __shfl_xor(s, d, 64);

  float deg = (float)(end - beg);
  float scale = (end > beg) ? (1.f/s) * (1.f/(1.f+deg)) : 0.f;

  float a0=0.f, a1=0.f, a2=0.f, a3=0.f;
  for (int i=beg; i<end; ++i){
    int e = eids[i];
    float al = __expf(score[e] - m);
    uint2 uv = *(const uint2*)(BE + (size_t)e*HD + l*4);
    a0 += al * bf2f((u16)(uv.x & 0xffff));
    a1 += al * bf2f((u16)(uv.x >> 16));
    a2 += al * bf2f((u16)(uv.y & 0xffff));
    a3 += al * bf2f((u16)(uv.y >> 16));
  }
  size_t o = (size_t)node*HD + l*4;
  a0 *= scale; a1 *= scale; a2 *= scale; a3 *= scale;
  bv[o+0]=a0; bv[o+1]=a1; bv[o+2]=a2; bv[o+3]=a3;
  uint2 p; p.x = (u32)f2bf(a0) | ((u32)f2bf(a1)<<16);
  p.y = (u32)f2bf(a2) | ((u32)f2bf(a3)<<16);
  *(uint2*)(bvb + o) = p;
}

// graph head: g_max + gather head/tail rows -> g_G [64][768] f32
__global__ void gmax_k(const float* __restrict__ bv, const int* __restrict__ heads,
                       const int* __restrict__ tails, float* __restrict__ gG){
  int g = blockIdx.x, col = threadIdx.x;
  float mx = -1e30f;
  const float* p = bv + (size_t)g*256*HD + col;
  for (int i=0; i<256; ++i) mx = fmaxf(mx, p[(size_t)i*HD]);
  gG[g*768 + col]       = mx;
  gG[g*768 + 256 + col] = bv[(size_t)heads[g]*HD + col];
  gG[g*768 + 512 + col] = bv[(size_t)tails[g]*HD + col];
}

__global__ void glog_k(const float* __restrict__ gG, const float* __restrict__ w1,
                       const float* __restrict__ b1, const float* __restrict__ w2,
                       const float* __restrict__ b2, float* __restrict__ logits){
  int g = blockIdx.x, n = threadIdx.x;
  float a = b1[n];
  const float* gg = gG + g*768;
  for (int k=0; k<768; ++k) a += gg[k] * w1[(size_t)k*HD + n];
  a = fmaxf(a, 0.f) * w2[n];
#pragma unroll
  for (int d=1; d<64; d<<=1) a += __shfl_xor(a, d, 64);
  __shared__ float red[4];
  if ((threadIdx.x & 63) == 0) red[threadIdx.x >> 6] = a;
  __syncthreads();
  if (threadIdx.x == 0) logits[g] = red[0]+red[1]+red[2]+red[3] + b2[0];
}

__global__ void gfin_k(const float* __restrict__ gG, const float* __restrict__ logits,
                       float* __restrict__ out){
  int tid = threadIdx.x;
  float m = -1e30f;
  for (int g=0; g<NG; ++g) m = fmaxf(m, logits[g]);
  float s = 0.f;
  for (int g=0; g<NG; ++g) s += __expf(logits[g] - m);
  float inv = 1.f/s;
  for (int j=tid; j<768; j+=256){
    float o = 0.f;
    for (int g=0; g<NG; ++g) o += __expf(logits[g]-m)*inv * gG[g*768 + j];
    out[j] = o;
  }
}

extern "C" void kernel_launch(void* const* d_in, const int* in_sizes, int n_in,
                              void* d_out, int out_size, void* d_ws, size_t ws_size,
                              hipStream_t stream)
{
  const float* ef    = (const float*)d_in[0];
  const float* gall  = (const float*)d_in[1];
  const float* ea_w1 = (const float*)d_in[2];
  const float* ea_b1 = (const float*)d_in[3];
  const float* ea_w2 = (const float*)d_in[4];
  const float* ea_b2 = (const float*)d_in[5];
  const float* eu_w1 = (const float*)d_in[6];
  const float* eu_b1 = (const float*)d_in[7];
  const float* eu_w2 = (const float*)d_in[8];
  const float* eu_b2 = (const float*)d_in[9];
  const float* gw_w1 = (const float*)d_in[10];
  const float* gw_b1 = (const float*)d_in[11];
  const float* gw_w2 = (const float*)d_in[12];
  const float* gw_b2 = (const float*)d_in[13];
  const float* ew_w  = (const float*)d_in[14];
  const float* ew_b  = (const float*)d_in[15];
  const int* eidx    = (const int*)d_in[16];
  const int* srcI    = eidx;
  const int* recvI   = eidx + NE;
  const int* ndeg    = (const int*)d_in[17];
  const int* batch   = (const int*)d_in[18];
  const int* heads   = (const int*)d_in[19];
  const int* tails   = (const int*)d_in[20];
  float* out = (float*)d_out;

  char* wsb = (char*)d_ws;
  size_t off = 0;
  auto alloc = [&](size_t sz)->char*{
    char* p = wsb + off; off = (off + sz + 255) & ~(size_t)255; return p;
  };
  u16*   BE    = (u16*)  alloc((size_t)NE*HD*2);
  u16*   Hh    = (u16*)  alloc((size_t)NE*HD*2);
  float* score = (float*)alloc((size_t)NE*4);
  u16*   P     = (u16*)  alloc((size_t)NN*HD*2);
  u16*   Q     = (u16*)  alloc((size_t)NN*HD*2);
  float* bv    = (float*)alloc((size_t)NN*HD*4);
  u16*   bvb   = (u16*)  alloc((size_t)NN*HD*2);
  int*   offs  = (int*)  alloc((size_t)(NN+1)*4);
  int*   cur   = (int*)  alloc((size_t)NN*4);
  int*   eids  = (int*)  alloc((size_t)NE*4);
  float* flags = (float*)alloc((size_t)NN*8);
  u16*   eaw1f = (u16*)  alloc((size_t)65536*2);
  u16*   w1af  = (u16*)  alloc((size_t)65536*2);
  u16*   w1bf  = (u16*)  alloc((size_t)65536*2);
  u16*   w1cf  = (u16*)  alloc((size_t)65536*2);
  u16*   euw2f = (u16*)  alloc((size_t)65536*2);
  float* gG    = (float*)alloc((size_t)NG*768*4);
  float* logits= (float*)alloc((size_t)NG*4);

  // one-time per launch: weight repacks + b_e init + flags + CSR
  repack_k<<<32,256,0,stream>>>(ea_w1, eaw1f);
  repack_k<<<32,256,0,stream>>>(eu_w1, w1af);              // rows 0..255   (src b_v part)
  repack_k<<<32,256,0,stream>>>(eu_w1 + 258*HD, w1bf);     // rows 258..513 (recv b_v part)
  repack_k<<<32,256,0,stream>>>(eu_w1 + 516*HD, w1cf);     // rows 516..771 (b_e part)
  repack_k<<<32,256,0,stream>>>(eu_w2, euw2f);
  initbe_k<<<NE*64/256,256,0,stream>>>(ef, gall, BE);
  flags_k<<<NN/256,256,0,stream>>>(batch, heads, tails, flags);
  scan_k<<<1,256,0,stream>>>(ndeg, offs, cur);
  fill_k<<<NE/256,256,0,stream>>>(recvI, cur, eids);

  for (int it=0; it<3; ++it){
    // score = sigmoid(relu(b_e@ea_w1+b1)@ea_w2+b2), second layer fused in-register
    gemm_k<MODE_SCORE><<<NE/128,256,0,stream>>>(BE, eaw1f, score, nullptr,
        ea_b1, ea_w2, ea_b2, nullptr, nullptr, nullptr, nullptr, nullptr, nullptr);
    // scatter-softmax + degree-normalized aggregation -> b_v (f32 + bf16)
    agg_k<<<NN/4,256,0,stream>>>(score, BE, offs, eids, bv, bvb);
    // P = r_v@W1a + b1 ; Q = r_v@W1b  (head/tail rank-1 rows in epilogue)
    gemm_k<MODE_PQ><<<NN/128,256,0,stream>>>(bvb, w1af, nullptr, P,
        eu_b1, nullptr, nullptr, nullptr, nullptr, nullptr, nullptr, flags, eu_w1 + 256*HD);
    gemm_k<MODE_PQ><<<NN/128,256,0,stream>>>(bvb, w1bf, nullptr, Q,
        nullptr, nullptr, nullptr, nullptr, nullptr, nullptr, nullptr, flags, eu_w1 + 514*HD);
    // h = relu(b_e@W1c + P[src] + Q[recv])
    gemm_k<MODE_PRE><<<NE/128,256,0,stream>>>(BE, w1cf, nullptr, Hh,
        nullptr, nullptr, nullptr, P, Q, srcI, recvI, nullptr, nullptr);
    if (it < 2){
      // b_e = h@eu_w2 + b2
      gemm_k<MODE_OUT><<<NE/128,256,0,stream>>>(Hh, euw2f, nullptr, BE,
          eu_b2, nullptr, nullptr, nullptr, nullptr, nullptr, nullptr, nullptr, nullptr);
    } else {
      // final iter: fuse w_e = sigmoid((h@eu_w2+b2)@ew_w+ew_b); b_e never stored
      gemm_k<MODE_OUT_WE><<<NE/128,256,0,stream>>>(Hh, euw2f, out, nullptr,
          eu_b2, ew_w, ew_b, nullptr, nullptr, nullptr, nullptr, nullptr, nullptr);
    }
  }

  // graph head (f32 exact, tiny)
  gmax_k<<<NG,256,0,stream>>>(bv, heads, tails, gG);
  glog_k<<<NG,256,0,stream>>>(gG, gw_w1, gw_b1, gw_w2, gw_b2, logits);
  gfin_k<<<1,256,0,stream>>>(gG, logits, out + NE);
}

// Round 2
// 1547.010 us; speedup vs baseline: 1.1161x; 1.1161x over previous
//
#include <hip/hip_runtime.h>
#include <stdint.h>

typedef unsigned short u16;
typedef unsigned int   u32;

#define NN 16384   // nodes
#define NE 262144  // edges
#define NG 64      // graphs
#define HD 256     // hidden
#define KC 8       // K/32 (K=256 for every GEMM here)

typedef __attribute__((ext_vector_type(8))) short bfrag;  // 8 bf16 (4 VGPR)
typedef __attribute__((ext_vector_type(4))) float ffrag;  // 4 f32 acc

__device__ __forceinline__ float bf2f(u16 h){
  union { u32 u; float f; } v; v.u = ((u32)h) << 16; return v.f;
}
__device__ __forceinline__ u16 f2bf(float x){
  union { float f; u32 u; } v; v.f = x;
  u32 r = v.u + 0x7fffu + ((v.u >> 16) & 1u);
  return (u16)(r >> 16);
}
__device__ __forceinline__ float sigmoidf(float x){ return 1.f/(1.f+__expf(-x)); }

enum { MODE_SCORE=0, MODE_PRE=1, MODE_OUT=2, MODE_OUT_WE=3, MODE_PQ=4 };

// C[M x 256] = A[M x 256] @ B[256 x 256]  (A bf16 row-major, B pre-repacked frag layout)
// R1 restructure: wave tile = 32 rows x 128 cols (acc = 64 AGPRs, was 128) so that
// VGPR+AGPR <= 256 -> 2 waves/SIMD (R0 was 1 wave/SIMD, OccupancyPercent 11%).
// Block = 256 thr (4 waves): wave pair (w>>1) = 32-row group, (w&1) = column half.
// Per-row L2 B traffic unchanged vs R0 (each wave reads half of B for 32 rows).
template<int MODE>
__global__ __launch_bounds__(256, 2)
void gemm_k(const u16* __restrict__ A, const u16* __restrict__ Bf,
            float* __restrict__ outF, u16* __restrict__ outB,
            const float* __restrict__ bias, const float* __restrict__ vec,
            const float* __restrict__ scal,
            const u16* __restrict__ Pg, const u16* __restrict__ Qg,
            const int* __restrict__ srcI, const int* __restrict__ recvI,
            const float* __restrict__ flags, const float* __restrict__ ht)
{
  const int l    = threadIdx.x & 63;
  const int w    = threadIdx.x >> 6;
  const int q    = l >> 4;
  const int ml   = l & 15;
  const int half = w & 1;                       // column half: cols [half*128, half*128+128)
  const long rowBase = (long)blockIdx.x * 64 + (w >> 1) * 32;

  ffrag acc[2][8];
#pragma unroll
  for (int mt=0; mt<2; ++mt)
#pragma unroll
    for (int n=0; n<8; ++n) acc[mt][n] = (ffrag){0.f,0.f,0.f,0.f};

  const u16* Ar0 = A + (size_t)(rowBase + ml) * HD;
  const u16* Ar1 = Ar0 + (size_t)16 * HD;

#pragma unroll 1
  for (int c=0; c<KC; ++c){
    bfrag a0 = *(const bfrag*)(Ar0 + c*32 + q*8);
    bfrag a1 = *(const bfrag*)(Ar1 + c*32 + q*8);
    const bfrag* bp = (const bfrag*)(Bf + (size_t)c*8192 + l*8) + (size_t)half*8*64;
#pragma unroll
    for (int n=0; n<8; ++n){
      bfrag b = bp[n*64];
      acc[0][n] = __builtin_amdgcn_mfma_f32_16x16x32_bf16(a0, b, acc[0][n], 0, 0, 0);
      acc[1][n] = __builtin_amdgcn_mfma_f32_16x16x32_bf16(a1, b, acc[1][n], 0, 0, 0);
    }
  }

  if constexpr (MODE==MODE_SCORE || MODE==MODE_OUT_WE){
    // fused second layer: reduce over cols of relu(C+b1)*w2 (SCORE) or (C+b2)*ew_w (OUT_WE)
    float part[2][4] = {{0,0,0,0},{0,0,0,0}};
#pragma unroll
    for (int n=0; n<8; ++n){
      const int col = (half*8 + n)*16 + ml;
      const float bb = bias[col];
      const float vv = vec[col];
#pragma unroll
      for (int mt=0; mt<2; ++mt)
#pragma unroll
        for (int r=0; r<4; ++r){
          float x = acc[mt][n][r] + bb;
          if (MODE==MODE_SCORE) x = fmaxf(x, 0.f);
          part[mt][r] += x * vv;
        }
    }
#pragma unroll
    for (int mt=0; mt<2; ++mt)
#pragma unroll
      for (int r=0; r<4; ++r){
        float p = part[mt][r];
        p += __shfl_xor(p, 1, 64);
        p += __shfl_xor(p, 2, 64);
        p += __shfl_xor(p, 4, 64);
        p += __shfl_xor(p, 8, 64);
        part[mt][r] = p;
      }
    // cross-wave (column-half) combine through LDS: 4 waves x 32 row-partials
    __shared__ float sred[4][32];
    if (ml == 0){
#pragma unroll
      for (int mt=0; mt<2; ++mt)
#pragma unroll
        for (int r=0; r<4; ++r)
          sred[w][mt*16 + q*4 + r] = part[mt][r];
    }
    __syncthreads();
    if (threadIdx.x < 64){
      const int t = threadIdx.x;
      const int p2 = t >> 5, idx = t & 31;
      const float sc = scal[0];
      float v = sred[2*p2][idx] + sred[2*p2+1][idx];
      outF[(long)blockIdx.x*64 + t] = sigmoidf(v + sc);
    }
  } else if constexpr (MODE==MODE_OUT){
#pragma unroll
    for (int mt=0; mt<2; ++mt)
#pragma unroll
      for (int r=0; r<4; ++r){
        long row = rowBase + mt*16 + q*4 + r;
        u16* op = outB + (size_t)row*HD + half*128 + ml;
#pragma unroll
        for (int n=0; n<8; ++n)
          op[n*16] = f2bf(acc[mt][n][r] + bias[(half*8+n)*16 + ml]);
      }
  } else if constexpr (MODE==MODE_PRE){
    // h = relu(b_e@W1c + P[src] + Q[recv])   (b1 folded into P)
#pragma unroll
    for (int mt=0; mt<2; ++mt)
#pragma unroll
      for (int r=0; r<4; ++r){
        long row = rowBase + mt*16 + q*4 + r;
        const int si = srcI[row];
        const int ri = recvI[row];
        const u16* Pr = Pg + (size_t)si*HD + half*128 + ml;
        const u16* Qr = Qg + (size_t)ri*HD + half*128 + ml;
        u16* op = outB + (size_t)row*HD + half*128 + ml;
#pragma unroll
        for (int n=0; n<8; ++n){
          float v = acc[mt][n][r] + bf2f(Pr[n*16]) + bf2f(Qr[n*16]);
          op[n*16] = f2bf(fmaxf(v, 0.f));
        }
      }
  } else { // MODE_PQ: node GEMM + rank-1 head/tail rows (+optional bias)
#pragma unroll
    for (int mt=0; mt<2; ++mt)
#pragma unroll
      for (int r=0; r<4; ++r){
        long row = rowBase + mt*16 + q*4 + r;
        const float fh = flags[2*row];
        const float ft = flags[2*row+1];
        u16* op = outB + (size_t)row*HD + half*128 + ml;
#pragma unroll
        for (int n=0; n<8; ++n){
          const int col = (half*8+n)*16 + ml;
          float v = acc[mt][n][r] + fh*ht[col] + ft*ht[HD+col];
          if (bias) v += bias[col];
          op[n*16] = f2bf(v);
        }
      }
  }
}

// repack B[256 x 256] f32 row-major -> bf16 MFMA-fragment order:
// out[((c*16+n)*64+l)*8+j] = B[c*32+(l>>4)*8+j][n*16+(l&15)]
__global__ void repack_k(const float* __restrict__ B, u16* __restrict__ out){
  int t = blockIdx.x*256 + threadIdx.x;        // 8192 total
  int l = t & 63, n = (t>>6)&15, c = t>>10;
  int k0 = c*32 + ((l>>4)<<3), col = n*16 + (l&15);
#pragma unroll
  for (int j=0; j<8; ++j)
    out[(size_t)t*8 + j] = f2bf(B[(size_t)(k0+j)*HD + col]);
}

// b_e(iter0) = [edge_features | g_all] -> bf16 row-major
__global__ void initbe_k(const float* __restrict__ ef, const float* __restrict__ gall,
                         u16* __restrict__ BE){
  int t = blockIdx.x*256 + threadIdx.x;        // NE*64
  int e = t >> 6; int c4 = (t & 63) * 4;
  float4 v;
  if (c4 < 192) v = *(const float4*)(ef + (size_t)e*192 + c4);
  else          v = *(const float4*)(gall + (c4 - 192));
  u32 lo = (u32)f2bf(v.x) | ((u32)f2bf(v.y) << 16);
  u32 hi = (u32)f2bf(v.z) | ((u32)f2bf(v.w) << 16);
  uint2 o; o.x = lo; o.y = hi;
  *(uint2*)(BE + (size_t)e*HD + c4) = o;
}

__global__ void flags_k(const int* __restrict__ batch, const int* __restrict__ heads,
                        const int* __restrict__ tails, float* __restrict__ flags){
  int n = blockIdx.x*256 + threadIdx.x;
  int g = batch[n];
  flags[2*n]   = (n == heads[g]) ? 1.f : 0.f;
  flags[2*n+1] = (n == tails[g]) ? 1.f : 0.f;
}

// exclusive prefix sum of degrees -> CSR offsets (+ cursor copy), single block
__global__ void scan_k(const int* __restrict__ deg, int* __restrict__ offs,
                       int* __restrict__ cur){
  __shared__ int part[256];
  int tid = threadIdx.x;
  int base = tid * 64;
  int s = 0;
  for (int j=0; j<64; ++j) s += deg[base+j];
  part[tid] = s;
  __syncthreads();
  if (tid == 0){
    int run = 0;
    for (int i=0; i<256; ++i){ int t = part[i]; part[i] = run; run += t; }
  }
  __syncthreads();
  int run = part[tid];
  for (int j=0; j<64; ++j){
    offs[base+j] = run; cur[base+j] = run; run += deg[base+j];
  }
  if (tid == 255) offs[NN] = run;
}

__global__ void fill_k(const int* __restrict__ recv, int* __restrict__ cur,
                       int* __restrict__ eids){
  int e = blockIdx.x*256 + threadIdx.x;
  int r = recv[e];
  int p = atomicAdd(&cur[r], 1);
  eids[p] = e;
}

// per-node softmax over incoming edges + weighted aggregation, one wave per node
__global__ __launch_bounds__(256)
void agg_k(const float* __restrict__ score, const u16* __restrict__ BE,
           const int* __restrict__ offs, const int* __restrict__ eids,
           float* __restrict__ bv, u16* __restrict__ bvb){
  int node = blockIdx.x*4 + (threadIdx.x >> 6);
  int l = threadIdx.x & 63;
  int beg = offs[node], end = offs[node+1];

  float m = -1e30f;
  for (int i=beg+l; i<end; i+=64) m = fmaxf(m, score[eids[i]]);
#pragma unroll
  for (int d=1; d<64; d<<=1) m = fmaxf(m, __shfl_xor(m, d, 64));

  float s = 0.f;
  for (int i=beg+l; i<end; i+=64) s += __expf(score[eids[i]] - m);
#pragma unroll
  for (int d=1; d<64; d<<=1) s += __shfl_xor(s, d, 64);

  float deg = (float)(end - beg);
  float scale = (end > beg) ? (1.f/s) * (1.f/(1.f+deg)) : 0.f;

  float a0=0.f, a1=0.f, a2=0.f, a3=0.f;
  for (int i=beg; i<end; ++i){
    int e = eids[i];
    float al = __expf(score[e] - m);
    uint2 uv = *(const uint2*)(BE + (size_t)e*HD + l*4);
    a0 += al * bf2f((u16)(uv.x & 0xffff));
    a1 += al * bf2f((u16)(uv.x >> 16));
    a2 += al * bf2f((u16)(uv.y & 0xffff));
    a3 += al * bf2f((u16)(uv.y >> 16));
  }
  size_t o = (size_t)node*HD + l*4;
  a0 *= scale; a1 *= scale; a2 *= scale; a3 *= scale;
  bv[o+0]=a0; bv[o+1]=a1; bv[o+2]=a2; bv[o+3]=a3;
  uint2 p; p.x = (u32)f2bf(a0) | ((u32)f2bf(a1)<<16);
  p.y = (u32)f2bf(a2) | ((u32)f2bf(a3)<<16);
  *(uint2*)(bvb + o) = p;
}

// graph head: g_max + gather head/tail rows -> g_G [64][768] f32
__global__ void gmax_k(const float* __restrict__ bv, const int* __restrict__ heads,
                       const int* __restrict__ tails, float* __restrict__ gG){
  int g = blockIdx.x, col = threadIdx.x;
  float mx = -1e30f;
  const float* p = bv + (size_t)g*256*HD + col;
  for (int i=0; i<256; ++i) mx = fmaxf(mx, p[(size_t)i*HD]);
  gG[g*768 + col]       = mx;
  gG[g*768 + 256 + col] = bv[(size_t)heads[g]*HD + col];
  gG[g*768 + 512 + col] = bv[(size_t)tails[g]*HD + col];
}

__global__ void glog_k(const float* __restrict__ gG, const float* __restrict__ w1,
                       const float* __restrict__ b1, const float* __restrict__ w2,
                       const float* __restrict__ b2, float* __restrict__ logits){
  int g = blockIdx.x, n = threadIdx.x;
  float a = b1[n];
  const float* gg = gG + g*768;
  for (int k=0; k<768; ++k) a += gg[k] * w1[(size_t)k*HD + n];
  a = fmaxf(a, 0.f) * w2[n];
#pragma unroll
  for (int d=1; d<64; d<<=1) a += __shfl_xor(a, d, 64);
  __shared__ float red[4];
  if ((threadIdx.x & 63) == 0) red[threadIdx.x >> 6] = a;
  __syncthreads();
  if (threadIdx.x == 0) logits[g] = red[0]+red[1]+red[2]+red[3] + b2[0];
}

__global__ void gfin_k(const float* __restrict__ gG, const float* __restrict__ logits,
                       float* __restrict__ out){
  int tid = threadIdx.x;
  float m = -1e30f;
  for (int g=0; g<NG; ++g) m = fmaxf(m, logits[g]);
  float s = 0.f;
  for (int g=0; g<NG; ++g) s += __expf(logits[g] - m);
  float inv = 1.f/s;
  for (int j=tid; j<768; j+=256){
    float o = 0.f;
    for (int g=0; g<NG; ++g) o += __expf(logits[g]-m)*inv * gG[g*768 + j];
    out[j] = o;
  }
}

extern "C" void kernel_launch(void* const* d_in, const int* in_sizes, int n_in,
                              void* d_out, int out_size, void* d_ws, size_t ws_size,
                              hipStream_t stream)
{
  const float* ef    = (const float*)d_in[0];
  const float* gall  = (const float*)d_in[1];
  const float* ea_w1 = (const float*)d_in[2];
  const float* ea_b1 = (const float*)d_in[3];
  const float* ea_w2 = (const float*)d_in[4];
  const float* ea_b2 = (const float*)d_in[5];
  const float* eu_w1 = (const float*)d_in[6];
  const float* eu_b1 = (const float*)d_in[7];
  const float* eu_w2 = (const float*)d_in[8];
  const float* eu_b2 = (const float*)d_in[9];
  const float* gw_w1 = (const float*)d_in[10];
  const float* gw_b1 = (const float*)d_in[11];
  const float* gw_w2 = (const float*)d_in[12];
  const float* gw_b2 = (const float*)d_in[13];
  const float* ew_w  = (const float*)d_in[14];
  const float* ew_b  = (const float*)d_in[15];
  const int* eidx    = (const int*)d_in[16];
  const int* srcI    = eidx;
  const int* recvI   = eidx + NE;
  const int* ndeg    = (const int*)d_in[17];
  const int* batch   = (const int*)d_in[18];
  const int* heads   = (const int*)d_in[19];
  const int* tails   = (const int*)d_in[20];
  float* out = (float*)d_out;

  char* wsb = (char*)d_ws;
  size_t off = 0;
  auto alloc = [&](size_t sz)->char*{
    char* p = wsb + off; off = (off + sz + 255) & ~(size_t)255; return p;
  };
  u16*   BE    = (u16*)  alloc((size_t)NE*HD*2);
  u16*   Hh    = (u16*)  alloc((size_t)NE*HD*2);
  float* score = (float*)alloc((size_t)NE*4);
  u16*   P     = (u16*)  alloc((size_t)NN*HD*2);
  u16*   Q     = (u16*)  alloc((size_t)NN*HD*2);
  float* bv    = (float*)alloc((size_t)NN*HD*4);
  u16*   bvb   = (u16*)  alloc((size_t)NN*HD*2);
  int*   offs  = (int*)  alloc((size_t)(NN+1)*4);
  int*   cur   = (int*)  alloc((size_t)NN*4);
  int*   eids  = (int*)  alloc((size_t)NE*4);
  float* flags = (float*)alloc((size_t)NN*8);
  u16*   eaw1f = (u16*)  alloc((size_t)65536*2);
  u16*   w1af  = (u16*)  alloc((size_t)65536*2);
  u16*   w1bf  = (u16*)  alloc((size_t)65536*2);
  u16*   w1cf  = (u16*)  alloc((size_t)65536*2);
  u16*   euw2f = (u16*)  alloc((size_t)65536*2);
  float* gG    = (float*)alloc((size_t)NG*768*4);
  float* logits= (float*)alloc((size_t)NG*4);

  // one-time per launch: weight repacks + b_e init + flags + CSR
  repack_k<<<32,256,0,stream>>>(ea_w1, eaw1f);
  repack_k<<<32,256,0,stream>>>(eu_w1, w1af);              // rows 0..255   (src b_v part)
  repack_k<<<32,256,0,stream>>>(eu_w1 + 258*HD, w1bf);     // rows 258..513 (recv b_v part)
  repack_k<<<32,256,0,stream>>>(eu_w1 + 516*HD, w1cf);     // rows 516..771 (b_e part)
  repack_k<<<32,256,0,stream>>>(eu_w2, euw2f);
  initbe_k<<<NE*64/256,256,0,stream>>>(ef, gall, BE);
  flags_k<<<NN/256,256,0,stream>>>(batch, heads, tails, flags);
  scan_k<<<1,256,0,stream>>>(ndeg, offs, cur);
  fill_k<<<NE/256,256,0,stream>>>(recvI, cur, eids);

  for (int it=0; it<3; ++it){
    // score = sigmoid(relu(b_e@ea_w1+b1)@ea_w2+b2), second layer fused in-register
    gemm_k<MODE_SCORE><<<NE/64,256,0,stream>>>(BE, eaw1f, score, nullptr,
        ea_b1, ea_w2, ea_b2, nullptr, nullptr, nullptr, nullptr, nullptr, nullptr);
    // scatter-softmax + degree-normalized aggregation -> b_v (f32 + bf16)
    agg_k<<<NN/4,256,0,stream>>>(score, BE, offs, eids, bv, bvb);
    // P = r_v@W1a + b1 ; Q = r_v@W1b  (head/tail rank-1 rows in epilogue)
    gemm_k<MODE_PQ><<<NN/64,256,0,stream>>>(bvb, w1af, nullptr, P,
        eu_b1, nullptr, nullptr, nullptr, nullptr, nullptr, nullptr, flags, eu_w1 + 256*HD);
    gemm_k<MODE_PQ><<<NN/64,256,0,stream>>>(bvb, w1bf, nullptr, Q,
        nullptr, nullptr, nullptr, nullptr, nullptr, nullptr, nullptr, flags, eu_w1 + 514*HD);
    // h = relu(b_e@W1c + P[src] + Q[recv])
    gemm_k<MODE_PRE><<<NE/64,256,0,stream>>>(BE, w1cf, nullptr, Hh,
        nullptr, nullptr, nullptr, P, Q, srcI, recvI, nullptr, nullptr);
    if (it < 2){
      // b_e = h@eu_w2 + b2
      gemm_k<MODE_OUT><<<NE/64,256,0,stream>>>(Hh, euw2f, nullptr, BE,
          eu_b2, nullptr, nullptr, nullptr, nullptr, nullptr, nullptr, nullptr, nullptr);
    } else {
      // final iter: fuse w_e = sigmoid((h@eu_w2+b2)@ew_w+ew_b); b_e never stored
      gemm_k<MODE_OUT_WE><<<NE/64,256,0,stream>>>(Hh, euw2f, out, nullptr,
          eu_b2, ew_w, ew_b, nullptr, nullptr, nullptr, nullptr, nullptr, nullptr);
    }
  }

  // graph head (f32 exact, tiny)
  gmax_k<<<NG,256,0,stream>>>(bv, heads, tails, gG);
  glog_k<<<NG,256,0,stream>>>(gG, gw_w1, gw_b1, gw_w2, gw_b2, logits);
  gfin_k<<<1,256,0,stream>>>(gG, logits, out + NE);
}